// Round 11
// baseline (26.151 us; speedup 1.0000x reference)
//
#include <hip/hip_runtime.h>

// B=128, x1/x2/x3 (B,2048,7,7) f32, W (14,2048), b (14,)
// softmax over singleton axis == 1.0 exactly  =>  h = 2*x1 + x2  (x3 unused!)
// feats[b,n] = mean_c(2*x1 + x2) ; logits = feats @ W^T + b
// Output layout: logits (128*14) then feats (128*2048), f32 flat.
//
// Round-11: kill the gather dispatch. Round-10's proven 2-phase pipelined
// streamer (double-buffered LDS, prefetch-before-s_barrier, lgkmcnt-only
// drain) + fc partials atomicAdd'ed DIRECTLY into logits: 1024 blocks x 14
// = 14336 atomics over 112 lines = 128/line (round 2's disaster was 2048/
// line; 16x fewer => ~0.8us tail). Replay safety: hipMemsetAsync zeroes
// logits each call; blkin==0 block adds bias. No fences (r7), no coop
// launch (r6), no second data kernel.

#define FC_B 128
#define FC_N 2048
#define FC_J 14
#define TILE_ROWS 64
#define TILE_F (TILE_ROWS * 49)         // 3136 floats
#define TILE_V (TILE_F / 4)             // 784 float4
#define TPB 4                           // tiles per block
#define RPB (TPB * TILE_ROWS)           // 256 rows per block
#define NBLK (FC_B * FC_N / RPB)        // 1024 blocks = 4/CU, all resident
#define BPB (FC_N / RPB)                // 8 blocks per batch row

__global__ __launch_bounds__(256) void fused_kernel(
    const float* __restrict__ x1, const float* __restrict__ x2,
    const float* __restrict__ W, const float* __restrict__ bias,
    float* __restrict__ feats, float* __restrict__ logits)
{
    const int tid = threadIdx.x;
    __shared__ float buf[2][TILE_F];                 // 25088 B
    __shared__ __align__(16) float sf[RPB];          // 1024 B

    const float4* q1 = (const float4*)x1 + (size_t)blockIdx.x * (TPB * TILE_V);
    const float4* q2 = (const float4*)x2 + (size_t)blockIdx.x * (TPB * TILE_V);

    float4 r1a, r1b, r1c, r2a, r2b, r2c, tl1, tl2;

    // prologue: load tile 0 into registers
    r1a = q1[tid]; r1b = q1[tid + 256]; r1c = q1[tid + 512];
    r2a = q2[tid]; r2b = q2[tid + 256]; r2c = q2[tid + 512];
    if (tid < 16) { tl1 = q1[768 + tid]; tl2 = q2[768 + tid]; }

    const int row = tid >> 2;            // 0..63
    const int tt = tid & 3;

    #pragma unroll
    for (int t = 0; t < TPB; ++t) {
        // ---- combine 2*x1+x2 in registers, write to LDS buf[t&1] ----
        float4* smv = (float4*)buf[t & 1];
        float4 w0, w1, w2;
        w0.x = 2.f*r1a.x + r2a.x; w0.y = 2.f*r1a.y + r2a.y;
        w0.z = 2.f*r1a.z + r2a.z; w0.w = 2.f*r1a.w + r2a.w;
        w1.x = 2.f*r1b.x + r2b.x; w1.y = 2.f*r1b.y + r2b.y;
        w1.z = 2.f*r1b.z + r2b.z; w1.w = 2.f*r1b.w + r2b.w;
        w2.x = 2.f*r1c.x + r2c.x; w2.y = 2.f*r1c.y + r2c.y;
        w2.z = 2.f*r1c.z + r2c.z; w2.w = 2.f*r1c.w + r2c.w;
        smv[tid] = w0; smv[tid + 256] = w1; smv[tid + 512] = w2;
        if (tid < 16) {
            float4 wt;
            wt.x = 2.f*tl1.x + tl2.x; wt.y = 2.f*tl1.y + tl2.y;
            wt.z = 2.f*tl1.z + tl2.z; wt.w = 2.f*tl1.w + tl2.w;
            smv[768 + tid] = wt;
        }

        // ---- issue prefetch of tile t+1 BEFORE the barrier (stays in
        // flight: raw s_barrier drains lgkm only, not vmcnt) ----
        if (t < TPB - 1) {
            const float4* Q1 = q1 + (t + 1) * TILE_V;
            const float4* Q2 = q2 + (t + 1) * TILE_V;
            r1a = Q1[tid]; r1b = Q1[tid + 256]; r1c = Q1[tid + 512];
            r2a = Q2[tid]; r2b = Q2[tid + 256]; r2c = Q2[tid + 512];
            if (tid < 16) { tl1 = Q1[768 + tid]; tl2 = Q2[768 + tid]; }
        }

        asm volatile("s_waitcnt lgkmcnt(0)" ::: "memory");
        __builtin_amdgcn_s_barrier();

        // ---- row reduce from buf[t&1]: 4 threads/row ----
        const float* rp = buf[t & 1] + row * 49;
        float v = 0.f;
        #pragma unroll
        for (int k = 0; k < 12; ++k)
            v += rp[tt + 4 * k];
        if (tt == 0) v += rp[48];
        v += __shfl_xor(v, 1, 4);
        v += __shfl_xor(v, 2, 4);
        if (tt == 0) sf[t * TILE_ROWS + row] = v * (1.0f / 49.0f);
        // next iteration's lgkmcnt(0)+barrier protects buf reuse (WAR) and
        // orders sf writes; double buffer makes 1 barrier/iter sufficient.
    }

    asm volatile("s_waitcnt lgkmcnt(0)" ::: "memory");
    __builtin_amdgcn_s_barrier();

    // ---- coalesced feats write: 64 lanes x float4 = 256 rows ----
    if (tid < 64)
        ((float4*)(feats + (size_t)blockIdx.x * RPB))[tid] =
            ((const float4*)sf)[tid];

    // ---- fc: 16-lane segmented dot per j, atomicAdd straight to logits ----
    if (tid < 224) {
        const int j = tid >> 4;              // 0..13
        const int s = tid & 15;
        const int bb = blockIdx.x >> 3;      // batch index (8 blocks/batch)
        const int blkin = blockIdx.x & (BPB - 1);
        const float* wrow = W + j * FC_N + blkin * RPB;   // W is L2-resident
        float acc = 0.f;
        #pragma unroll
        for (int k = 0; k < 16; ++k)
            acc += sf[s + 16 * k] * wrow[s + 16 * k];
        acc += __shfl_xor(acc, 1, 16);
        acc += __shfl_xor(acc, 2, 16);
        acc += __shfl_xor(acc, 4, 16);
        acc += __shfl_xor(acc, 8, 16);
        if (s == 0) {
            if (blkin == 0) acc += bias[j];  // bias folded in exactly once
            atomicAdd(&logits[bb * FC_J + j], acc);  // 128 adds/line, spread
        }
    }
}

extern "C" void kernel_launch(void* const* d_in, const int* in_sizes, int n_in,
                              void* d_out, int out_size, void* d_ws, size_t ws_size,
                              hipStream_t stream) {
    const float* x1 = (const float*)d_in[0];
    const float* x2 = (const float*)d_in[1];
    // d_in[2] = x3 — provably unused (softmax over singleton axis == 1)
    const float* W = (const float*)d_in[3];
    const float* bias = (const float*)d_in[4];

    float* out = (float*)d_out;
    float* logits = out;                 // 128*14
    float* feats = out + FC_B * FC_J;    // 128*2048

    // zero logits each call (graph-legal memset node) so atomic accumulation
    // is replay-deterministic in semantics
    hipMemsetAsync(logits, 0, FC_B * FC_J * sizeof(float), stream);
    fused_kernel<<<NBLK, 256, 0, stream>>>(x1, x2, W, bias, feats, logits);
}

// Round 12
// 22.844 us; speedup vs baseline: 1.1448x; 1.1448x over previous
//
#include <hip/hip_runtime.h>

// B=128, x1/x2/x3 (B,2048,7,7) f32, W (14,2048), b (14,)
// softmax over singleton axis == 1.0 exactly  =>  h = 2*x1 + x2  (x3 unused!)
// feats[b,n] = mean_c(2*x1 + x2) ; logits = feats @ W^T + b
// Output layout: logits (128*14) then feats (128*2048), f32 flat.
//
// Round-12: barrier-free per-wave pipeline. Round 10 (22.56us, best) still
// lockstepped 4 waves at an s_barrier every tile. Here each wave owns
// 4 subtiles of 16 rows (784 floats = 196 float4) with wave-PRIVATE
// double-buffered LDS: load(s+1) issued -> combine(s)->LDS -> lgkmcnt(0)
// (wave-local; DS unit is in-order per wave, no s_barrier needed) ->
// 4-lane/row reduce. Zero block barriers in the data loop; one
// __syncthreads before the fc phase. Reduce-read banks = (17*row + t)
// mod 32 = exactly 2 lanes/bank = free (m136). Gather kernel unchanged
// (r11 proved tiny memset+atomics costs more than the gather dispatch).

#define FC_B 128
#define FC_N 2048
#define FC_J 14
#define SUBT 4                       // subtiles per wave
#define SUB_ROWS 16
#define SUB_F (SUB_ROWS * 49)        // 784 floats
#define SUB_V (SUB_F / 4)            // 196 float4
#define WCHUNK_V (SUBT * SUB_V)      // 784 float4 per wave
#define RPB 256                      // rows per block (4 waves * 64)
#define NBLK (FC_B * FC_N / RPB)     // 1024 blocks
#define BPB (FC_N / RPB)             // 8 blocks per batch row

__global__ __launch_bounds__(256) void fused_kernel(
    const float* __restrict__ x1, const float* __restrict__ x2,
    const float* __restrict__ W,
    float* __restrict__ feats, float* __restrict__ part)
{
    const int tid = threadIdx.x;
    const int w = tid >> 6;          // wave 0..3
    const int lane = tid & 63;
    __shared__ float buf[4][2][SUB_F];               // 25088 B, wave-private
    __shared__ __align__(16) float sf[RPB];          // 1024 B

    // wave w owns rows blockIdx*256 + w*64 .. +63 (4 subtiles of 16)
    const float4* q1 = (const float4*)x1
                     + (size_t)blockIdx.x * (RPB * 49 / 4) + w * WCHUNK_V;
    const float4* q2 = (const float4*)x2
                     + (size_t)blockIdx.x * (RPB * 49 / 4) + w * WCHUNK_V;

    // two staging register sets (static indices via full unroll)
    float4 a0[2], a1[2], a2[2], at[2], c0[2], c1[2], c2[2], ct[2];

    // prologue: subtile 0 into set 0
    a0[0] = q1[lane]; a1[0] = q1[lane + 64]; a2[0] = q1[lane + 128];
    c0[0] = q2[lane]; c1[0] = q2[lane + 64]; c2[0] = q2[lane + 128];
    if (lane < 4) { at[0] = q1[192 + lane]; ct[0] = q2[192 + lane]; }

    const int r = lane >> 2;         // row within subtile 0..15
    const int t4 = lane & 3;

    #pragma unroll
    for (int s = 0; s < SUBT; ++s) {
        const int cur = s & 1, nxt = cur ^ 1;

        // issue next subtile's loads first (stay in flight past the
        // combine's counted-vmcnt wait for the current set)
        if (s < SUBT - 1) {
            const float4* Q1 = q1 + (s + 1) * SUB_V;
            const float4* Q2 = q2 + (s + 1) * SUB_V;
            a0[nxt] = Q1[lane]; a1[nxt] = Q1[lane + 64]; a2[nxt] = Q1[lane + 128];
            c0[nxt] = Q2[lane]; c1[nxt] = Q2[lane + 64]; c2[nxt] = Q2[lane + 128];
            if (lane < 4) { at[nxt] = Q1[192 + lane]; ct[nxt] = Q2[192 + lane]; }
        }

        // combine 2*x1+x2 -> wave-private LDS buffer
        float4* smv = (float4*)buf[w][cur];
        float4 w0, w1, w2;
        w0.x = 2.f*a0[cur].x + c0[cur].x; w0.y = 2.f*a0[cur].y + c0[cur].y;
        w0.z = 2.f*a0[cur].z + c0[cur].z; w0.w = 2.f*a0[cur].w + c0[cur].w;
        w1.x = 2.f*a1[cur].x + c1[cur].x; w1.y = 2.f*a1[cur].y + c1[cur].y;
        w1.z = 2.f*a1[cur].z + c1[cur].z; w1.w = 2.f*a1[cur].w + c1[cur].w;
        w2.x = 2.f*a2[cur].x + c2[cur].x; w2.y = 2.f*a2[cur].y + c2[cur].y;
        w2.z = 2.f*a2[cur].z + c2[cur].z; w2.w = 2.f*a2[cur].w + c2[cur].w;
        smv[lane] = w0; smv[lane + 64] = w1; smv[lane + 128] = w2;
        if (lane < 4) {
            float4 wt;
            wt.x = 2.f*at[cur].x + ct[cur].x; wt.y = 2.f*at[cur].y + ct[cur].y;
            wt.z = 2.f*at[cur].z + ct[cur].z; wt.w = 2.f*at[cur].w + ct[cur].w;
            smv[192 + lane] = wt;
        }

        // wave-local ordering only; DS pipe is in-order per wave
        asm volatile("s_waitcnt lgkmcnt(0)" ::: "memory");

        // 4-lane/row reduce from wave-private buffer
        const float* rp = buf[w][cur] + r * 49;
        float v = 0.f;
        #pragma unroll
        for (int k = 0; k < 12; ++k)
            v += rp[t4 + 4 * k];
        if (t4 == 0) v += rp[48];
        v += __shfl_xor(v, 1, 4);
        v += __shfl_xor(v, 2, 4);
        if (t4 == 0) sf[w * 64 + s * SUB_ROWS + r] = v * (1.0f / 49.0f);
    }

    __syncthreads();   // sf complete across all 4 waves

    // ---- coalesced feats write: 64 lanes x float4 = 256 rows ----
    if (tid < 64)
        ((float4*)(feats + (size_t)blockIdx.x * RPB))[tid] =
            ((const float4*)sf)[tid];

    // ---- fc partials: 224 threads, 16-lane segmented dot ----
    if (tid < 224) {
        const int j = tid >> 4;              // 0..13
        const int s16 = tid & 15;
        const int bb = blockIdx.x >> 3;      // batch index (8 blocks/batch)
        const int blkin = blockIdx.x & (BPB - 1);
        const float* wrow = W + j * FC_N + blkin * RPB;   // W is L2-resident
        float acc = 0.f;
        #pragma unroll
        for (int k = 0; k < 16; ++k)
            acc += sf[s16 + 16 * k] * wrow[s16 + 16 * k];
        acc += __shfl_xor(acc, 1, 16);
        acc += __shfl_xor(acc, 2, 16);
        acc += __shfl_xor(acc, 4, 16);
        acc += __shfl_xor(acc, 8, 16);
        if (s16 == 0)
            part[((bb * FC_J + j) << 3) + blkin] = acc;   // part[b][j][blkin]
    }
}

__global__ __launch_bounds__(256) void gather_kernel(const float* __restrict__ part,
                                                     const float* __restrict__ bias,
                                                     float* __restrict__ logits) {
    const int idx = blockIdx.x * 256 + threadIdx.x;
    if (idx >= FC_B * FC_J) return;
    const float4 p0 = ((const float4*)(part + ((size_t)idx << 3)))[0];
    const float4 p1 = ((const float4*)(part + ((size_t)idx << 3)))[1];
    logits[idx] = p0.x + p0.y + p0.z + p0.w
                + p1.x + p1.y + p1.z + p1.w + bias[idx % FC_J];
}

extern "C" void kernel_launch(void* const* d_in, const int* in_sizes, int n_in,
                              void* d_out, int out_size, void* d_ws, size_t ws_size,
                              hipStream_t stream) {
    const float* x1 = (const float*)d_in[0];
    const float* x2 = (const float*)d_in[1];
    // d_in[2] = x3 — provably unused (softmax over singleton axis == 1)
    const float* W = (const float*)d_in[3];
    const float* bias = (const float*)d_in[4];

    float* out = (float*)d_out;
    float* logits = out;                 // 128*14
    float* feats = out + FC_B * FC_J;    // 128*2048

    float* part = (float*)d_ws;          // 128*14*8*4 = 57 KB scratch

    fused_kernel<<<NBLK, 256, 0, stream>>>(x1, x2, W, feats, part);
    gather_kernel<<<(FC_B * FC_J + 255) / 256, 256, 0, stream>>>(part, bias, logits);
}